// Round 6
// baseline (334.548 us; speedup 1.0000x reference)
//
#include <hip/hip_runtime.h>

#define Ecnt 512
#define Dd 64
#define Aa 8
#define Hh 256
#define Nn 16
#define Tt 128
#define NH 144            // 16 time outputs + 128 anchor outputs
#define SF2c 0.01f
#define SN2c 0.01f
#define NEGHALF_INV_L2 (-50.0f)   // -0.5 / 0.1^2

// ws layout (floats)
#define OFF_W1T 0                          // [Dd][Hh]
#define OFF_W2T (OFF_W1T + Dd * Hh)        // [Hh][Hh]
#define OFF_WHT (OFF_W2T + Hh * Hh)        // [Hh][NH]
#define OFF_BH  (OFF_WHT + Hh * NH)        // [NH]
#define OFF_TT  (OFF_BH + NH)              // [Ecnt][Nn] (reserved)
#define OFF_KS  (OFF_TT + Ecnt * Nn)       // [Ecnt][Tt][Nn]  Ks
#define OFF_V   (OFF_KS + Ecnt * Tt * Nn)  // [Ecnt][Nn][Tt]  V = K^-1 Ks^T
#define WS_FLOATS (OFF_V + Ecnt * Nn * Tt)

__global__ void prep(const float* __restrict__ W1, const float* __restrict__ W2,
                     const float* __restrict__ Wt, const float* __restrict__ Wa,
                     const float* __restrict__ bt, const float* __restrict__ ba,
                     float* __restrict__ ws) {
    int id = blockIdx.x * blockDim.x + threadIdx.x;
    if (id < Dd * Hh) {
        int k = id >> 8, o = id & 255;
        ws[OFF_W1T + id] = W1[o * Dd + k];
    } else if (id < OFF_WHT) {
        int r = id - OFF_W2T; int k = r >> 8, o = r & 255;
        ws[id] = W2[o * Hh + k];
    } else if (id < OFF_BH) {
        int r = id - OFF_WHT; int k = r / NH, j = r % NH;
        ws[id] = (j < Nn) ? Wt[j * Hh + k] : Wa[(j - Nn) * Hh + k];
    } else if (id < OFF_TT) {
        int j = id - OFF_BH;
        ws[id] = (j < Nn) ? bt[j] : ba[j - Nn];
    }
}

// ---- k1: one wave per example; no barriers, no LDS; all cross-lane via shfl ----
__global__ __launch_bounds__(64, 1) void grp_solve_wave(
    const float* __restrict__ x,
    const float* __restrict__ b1, const float* __restrict__ b2,
    const float* __restrict__ tarr, float* __restrict__ ws,
    float* __restrict__ out_mu)
{
    const int e = blockIdx.x;
    const int l = threadIdx.x;

    const float4* __restrict__ W1T4 = (const float4*)(ws + OFF_W1T);
    const float4* __restrict__ W2T4 = (const float4*)(ws + OFF_W2T);
    const float4* __restrict__ WHT4 = (const float4*)(ws + OFF_WHT);
    const float*  __restrict__ BH   = ws + OFF_BH;

    const float xreg = x[e * Dd + l];
    const float2 tq2 = *(const float2*)&tarr[2 * l];

    // ---- layer 1: lane owns neurons 4l..4l+3 ----
    float4 bv = *(const float4*)&b1[4 * l];
    float a0 = bv.x, a1 = bv.y, a2 = bv.z, a3 = bv.w;
    #pragma unroll 8
    for (int k = 0; k < Dd; ++k) {
        float hk = __shfl(xreg, k);
        float4 w = W1T4[k * 64 + l];
        a0 += w.x * hk; a1 += w.y * hk; a2 += w.z * hk; a3 += w.w * hk;
    }
    float h0 = tanhf(a0), h1 = tanhf(a1), h2 = tanhf(a2), h3 = tanhf(a3);

    // ---- layer 2 ----
    bv = *(const float4*)&b2[4 * l];
    a0 = bv.x; a1 = bv.y; a2 = bv.z; a3 = bv.w;
    #pragma unroll 4
    for (int k0 = 0; k0 < 64; ++k0) {
        float g0 = __shfl(h0, k0), g1 = __shfl(h1, k0);
        float g2 = __shfl(h2, k0), g3 = __shfl(h3, k0);
        float4 w;
        w = W2T4[(4 * k0 + 0) * 64 + l]; a0 += w.x * g0; a1 += w.y * g0; a2 += w.z * g0; a3 += w.w * g0;
        w = W2T4[(4 * k0 + 1) * 64 + l]; a0 += w.x * g1; a1 += w.y * g1; a2 += w.z * g1; a3 += w.w * g1;
        w = W2T4[(4 * k0 + 2) * 64 + l]; a0 += w.x * g2; a1 += w.y * g2; a2 += w.z * g2; a3 += w.w * g2;
        w = W2T4[(4 * k0 + 3) * 64 + l]; a0 += w.x * g3; a1 += w.y * g3; a2 += w.z * g3; a3 += w.w * g3;
    }
    h0 = tanhf(a0); h1 = tanhf(a1); h2 = tanhf(a2); h3 = tanhf(a3);

    // ---- heads: 144 outputs, lanes 0..35 own 4 consecutive each ----
    float c0 = 0.f, c1 = 0.f, c2 = 0.f, c3 = 0.f;
    if (l < 36) {
        float4 bh = *(const float4*)&BH[4 * l];
        c0 = bh.x; c1 = bh.y; c2 = bh.z; c3 = bh.w;
    }
    #pragma unroll 4
    for (int k0 = 0; k0 < 64; ++k0) {
        float g0 = __shfl(h0, k0), g1 = __shfl(h1, k0);
        float g2 = __shfl(h2, k0), g3 = __shfl(h3, k0);
        if (l < 36) {
            float4 w;
            w = WHT4[(4 * k0 + 0) * 36 + l]; c0 += w.x * g0; c1 += w.y * g0; c2 += w.z * g0; c3 += w.w * g0;
            w = WHT4[(4 * k0 + 1) * 36 + l]; c0 += w.x * g1; c1 += w.y * g1; c2 += w.z * g1; c3 += w.w * g1;
            w = WHT4[(4 * k0 + 2) * 36 + l]; c0 += w.x * g2; c1 += w.y * g2; c2 += w.z * g2; c3 += w.w * g2;
            w = WHT4[(4 * k0 + 3) * 36 + l]; c0 += w.x * g3; c1 += w.y * g3; c2 += w.z * g3; c3 += w.w * g3;
        }
    }

    // ---- broadcast train times tt[0..15] (live in lanes 0..3) ----
    float ttv[16];
    #pragma unroll
    for (int i = 0; i < 16; ++i) {
        float src = ((i & 3) == 0) ? c0 : ((i & 3) == 1) ? c1 : ((i & 3) == 2) ? c2 : c3;
        ttv[i] = __shfl(src, i >> 2);
    }
    // alpha RHS: lane 48+a gathers y[a][0..15] (H[16+16a+i] lives at lane 4+4a+(i>>2))
    float z2[16];
    #pragma unroll
    for (int i = 0; i < 16; ++i) {
        int src = (4 + 4 * (l - 48) + (i >> 2)) & 63;
        float v = ((i & 3) == 0) ? c0 : ((i & 3) == 1) ? c1 : ((i & 3) == 2) ? c2 : c3;
        z2[i] = __shfl(v, src);
    }

    // ---- K row for lane i (i<16): Krow[j] = k(tt_i, tt_j) + ridge ----
    float tsel = ttv[0];
    #pragma unroll
    for (int i = 1; i < 16; ++i) tsel = (l == i) ? ttv[i] : tsel;
    float Krow[16];
    #pragma unroll
    for (int j = 0; j < 16; ++j) {
        float d = tsel - ttv[j];
        Krow[j] = SF2c * __expf(NEGHALF_INV_L2 * d * d) + ((l == j) ? SN2c : 0.f);
    }

    // ---- register Cholesky: lane i owns row i of L ----
    float Lrow[16];
    #pragma unroll
    for (int j = 0; j < 16; ++j) {
        float s = Krow[j];
        #pragma unroll
        for (int k = 0; k < j; ++k) {
            float Ljk = __shfl(Lrow[k], j);
            s -= Lrow[k] * Ljk;
        }
        float dj = __shfl(s, j);          // pivot value (valid: lane j has i==j)
        float dsq = sqrtf(dj);
        float rinv = 1.0f / dsq;
        Lrow[j] = (l == j) ? dsq : s * rinv;
    }

    // ---- Ks rows for this lane's two query points ----
    float Ksr0[16], Ksr1[16];
    #pragma unroll
    for (int i = 0; i < 16; ++i) {
        float d0 = tq2.x - ttv[i];
        float d1 = tq2.y - ttv[i];
        Ksr0[i] = SF2c * __expf(NEGHALF_INV_L2 * d0 * d0);
        Ksr1[i] = SF2c * __expf(NEGHALF_INV_L2 * d1 * d1);
    }
    float z0[16], z1[16];
    #pragma unroll
    for (int i = 0; i < 16; ++i) { z0[i] = Ksr0[i]; z1[i] = Ksr1[i]; }

    // ---- forward solve L z = b (3 RHS per lane) ----
    #pragma unroll
    for (int i = 0; i < 16; ++i) {
        #pragma unroll
        for (int k = 0; k < i; ++k) {
            float Lik = __shfl(Lrow[k], i);
            z0[i] -= Lik * z0[k];
            z1[i] -= Lik * z1[k];
            z2[i] -= Lik * z2[k];
        }
        float Lii = __shfl(Lrow[i], i);
        float r = 1.0f / Lii;
        z0[i] *= r; z1[i] *= r; z2[i] *= r;
    }
    // ---- backward solve L^T w = z ----
    #pragma unroll
    for (int i = 15; i >= 0; --i) {
        #pragma unroll
        for (int k = i + 1; k < 16; ++k) {
            float Lki = __shfl(Lrow[i], k);   // L[k][i]
            z0[i] -= Lki * z0[k];
            z1[i] -= Lki * z1[k];
            z2[i] -= Lki * z2[k];
        }
        float Lii = __shfl(Lrow[i], i);
        float r = 1.0f / Lii;
        z0[i] *= r; z1[i] *= r; z2[i] *= r;
    }

    // ---- store V[i][q] (q = 2l, 2l+1) and Ks rows for the cov kernel ----
    float* __restrict__ wsV = ws + OFF_V + (size_t)e * (Nn * Tt);
    #pragma unroll
    for (int i = 0; i < 16; ++i) {
        float2 p; p.x = z0[i]; p.y = z1[i];
        *(float2*)&wsV[i * Tt + 2 * l] = p;
    }
    float* __restrict__ wsK = ws + OFF_KS + (size_t)e * (Tt * Nn);
    #pragma unroll
    for (int m = 0; m < 4; ++m) {
        float4 p0; p0.x = Ksr0[4*m+0]; p0.y = Ksr0[4*m+1]; p0.z = Ksr0[4*m+2]; p0.w = Ksr0[4*m+3];
        *(float4*)&wsK[(2 * l) * Nn + 4 * m] = p0;
        float4 p1; p1.x = Ksr1[4*m+0]; p1.y = Ksr1[4*m+1]; p1.z = Ksr1[4*m+2]; p1.w = Ksr1[4*m+3];
        *(float4*)&wsK[(2 * l + 1) * Nn + 4 * m] = p1;
    }

    // ---- mu[a][q] = Ks[q,:] . alpha[a,:]  (alpha[a] lives in lane 48+a's z2) ----
    float* __restrict__ mub = out_mu + (size_t)e * (Aa * Tt);
    #pragma unroll
    for (int a = 0; a < Aa; ++a) {
        float m0 = 0.f, m1 = 0.f;
        #pragma unroll
        for (int i = 0; i < 16; ++i) {
            float al = __shfl(z2[i], 48 + a);
            m0 += Ksr0[i] * al;
            m1 += Ksr1[i] * al;
        }
        float2 p; p.x = m0; p.y = m1;
        *(float2*)&mub[a * Tt + 2 * l] = p;
    }
}

// ---- k2: cov = Kss - Ks.V, written 8x; block = (e, 32-row chunk) [unchanged] ----
__global__ __launch_bounds__(256, 4) void grp_cov(
    const float* __restrict__ ws, const float* __restrict__ tarr,
    float* __restrict__ out_cov)
{
    const int b  = blockIdx.x;
    const int e  = b >> 2;
    const int ch = b & 3;
    const int tid = threadIdx.x;

    __shared__ __align__(16) float Vs[Nn][Tt];      // 8 KB
    __shared__ __align__(16) float Ksl[32][Nn];     // 2 KB
    __shared__ float tqs[Tt];

    {
        const float4* sV = (const float4*)(ws + OFF_V + (size_t)e * (Nn * Tt));
        float4* dV = (float4*)&Vs[0][0];
        dV[tid] = sV[tid];
        dV[tid + 256] = sV[tid + 256];
        if (tid < 128) {
            const float4* sK = (const float4*)(ws + OFF_KS + (size_t)e * (Tt * Nn) + (size_t)ch * 32 * Nn);
            ((float4*)&Ksl[0][0])[tid] = sK[tid];
        }
        if (tid < Tt) tqs[tid] = tarr[tid];
    }
    __syncthreads();

    const int q4 = (tid & 31) * 4;
    const int pr = tid >> 5;
    float vq[Nn][4];
    #pragma unroll
    for (int i = 0; i < Nn; ++i) {
        float4 vv = *(const float4*)&Vs[i][q4];
        vq[i][0] = vv.x; vq[i][1] = vv.y; vq[i][2] = vv.z; vq[i][3] = vv.w;
    }
    const float tqq0 = tqs[q4 + 0], tqq1 = tqs[q4 + 1], tqq2 = tqs[q4 + 2], tqq3 = tqs[q4 + 3];
    float* covb = out_cov + (size_t)e * (Aa * Tt * Tt);

    #pragma unroll
    for (int pp = 0; pp < 4; ++pp) {
        const int lp = pr * 4 + pp;
        const int p  = ch * 32 + lp;
        const float tqp = tqs[p];
        float d0 = tqp - tqq0, d1 = tqp - tqq1, d2 = tqp - tqq2, d3 = tqp - tqq3;
        float a0 = SF2c * __expf(NEGHALF_INV_L2 * d0 * d0);
        float a1 = SF2c * __expf(NEGHALF_INV_L2 * d1 * d1);
        float a2 = SF2c * __expf(NEGHALF_INV_L2 * d2 * d2);
        float a3 = SF2c * __expf(NEGHALF_INV_L2 * d3 * d3);
        #pragma unroll
        for (int i = 0; i < Nn; ++i) {
            float ks = Ksl[lp][i];
            a0 -= ks * vq[i][0];
            a1 -= ks * vq[i][1];
            a2 -= ks * vq[i][2];
            a3 -= ks * vq[i][3];
        }
        float4 pk; pk.x = a0; pk.y = a1; pk.z = a2; pk.w = a3;
        const size_t ro = (size_t)p * Tt + q4;
        #pragma unroll
        for (int a = 0; a < Aa; ++a) {
            *(float4*)(covb + (size_t)a * (Tt * Tt) + ro) = pk;
        }
    }
}

extern "C" void kernel_launch(void* const* d_in, const int* in_sizes, int n_in,
                              void* d_out, int out_size, void* d_ws, size_t ws_size,
                              hipStream_t stream) {
    (void)in_sizes; (void)n_in; (void)out_size; (void)ws_size;
    const float* x  = (const float*)d_in[0];
    // d_in[1] (a) and d_in[2] (da) unused by the reference
    const float* W1 = (const float*)d_in[3];
    const float* b1 = (const float*)d_in[4];
    const float* W2 = (const float*)d_in[5];
    const float* b2 = (const float*)d_in[6];
    const float* Wt = (const float*)d_in[7];
    const float* bt = (const float*)d_in[8];
    const float* Wa = (const float*)d_in[9];
    const float* ba = (const float*)d_in[10];
    const float* ta = (const float*)d_in[11];
    float* mu  = (float*)d_out;
    float* cov = mu + (size_t)Ecnt * Aa * Tt;
    float* wsf = (float*)d_ws;

    prep<<<(OFF_TT + 255) / 256, 256, 0, stream>>>(W1, W2, Wt, Wa, bt, ba, wsf);
    grp_solve_wave<<<Ecnt, 64, 0, stream>>>(x, b1, b2, ta, wsf, mu);
    grp_cov<<<Ecnt * 4, 256, 0, stream>>>(wsf, ta, cov);
}

// Round 7
// 331.222 us; speedup vs baseline: 1.0100x; 1.0100x over previous
//
#include <hip/hip_runtime.h>

#define Ecnt 512
#define Dd 64
#define Aa 8
#define Hh 256
#define Nn 16
#define Tt 128
#define NH 144            // 16 time outputs + 128 anchor outputs
#define SF2c 0.01f
#define SN2c 0.01f
#define NEGHALF_INV_L2 (-50.0f)   // -0.5 / 0.1^2

// ws layout (floats)
#define OFF_W1T 0                          // [Dd][Hh]
#define OFF_W2T (OFF_W1T + Dd * Hh)        // [Hh][Hh]
#define OFF_WHT (OFF_W2T + Hh * Hh)        // [Hh][NH]
#define OFF_BH  (OFF_WHT + Hh * NH)        // [NH]
#define OFF_TT  (OFF_BH + NH)              // [Ecnt][Nn] (reserved)
#define OFF_KS  (OFF_TT + Ecnt * Nn)       // [Ecnt][Tt][Nn]  Ks
#define OFF_V   (OFF_KS + Ecnt * Tt * Nn)  // [Ecnt][Nn][Tt]  V = K^-1 Ks^T
#define WS_FLOATS (OFF_V + Ecnt * Nn * Tt)

__global__ void prep(const float* __restrict__ W1, const float* __restrict__ W2,
                     const float* __restrict__ Wt, const float* __restrict__ Wa,
                     const float* __restrict__ bt, const float* __restrict__ ba,
                     float* __restrict__ ws) {
    int id = blockIdx.x * blockDim.x + threadIdx.x;
    if (id < Dd * Hh) {
        int k = id >> 8, o = id & 255;
        ws[OFF_W1T + id] = W1[o * Dd + k];
    } else if (id < OFF_WHT) {
        int r = id - OFF_W2T; int k = r >> 8, o = r & 255;
        ws[id] = W2[o * Hh + k];
    } else if (id < OFF_BH) {
        int r = id - OFF_WHT; int k = r / NH, j = r % NH;
        ws[id] = (j < Nn) ? Wt[j * Hh + k] : Wa[(j - Nn) * Hh + k];
    } else if (id < OFF_TT) {
        int j = id - OFF_BH;
        ws[id] = (j < Nn) ? bt[j] : ba[j - Nn];
    }
}

// ---- k1: one wave per example; no barriers, no LDS; all cross-lane via shfl ----
__global__ __launch_bounds__(64, 1) void grp_solve_wave(
    const float* __restrict__ x,
    const float* __restrict__ b1, const float* __restrict__ b2,
    const float* __restrict__ tarr, float* __restrict__ ws,
    float* __restrict__ out_mu)
{
    const int e = blockIdx.x;
    const int l = threadIdx.x;

    const float4* __restrict__ W1T4 = (const float4*)(ws + OFF_W1T);
    const float4* __restrict__ W2T4 = (const float4*)(ws + OFF_W2T);
    const float4* __restrict__ WHT4 = (const float4*)(ws + OFF_WHT);
    const float*  __restrict__ BH   = ws + OFF_BH;

    const float xreg = x[e * Dd + l];
    const float2 tq2 = *(const float2*)&tarr[2 * l];

    // ---- layer 1: lane owns neurons 4l..4l+3 ----
    float4 bv = *(const float4*)&b1[4 * l];
    float a0 = bv.x, a1 = bv.y, a2 = bv.z, a3 = bv.w;
    #pragma unroll 8
    for (int k = 0; k < Dd; ++k) {
        float hk = __shfl(xreg, k);
        float4 w = W1T4[k * 64 + l];
        a0 += w.x * hk; a1 += w.y * hk; a2 += w.z * hk; a3 += w.w * hk;
    }
    float h0 = tanhf(a0), h1 = tanhf(a1), h2 = tanhf(a2), h3 = tanhf(a3);

    // ---- layer 2 ----
    bv = *(const float4*)&b2[4 * l];
    a0 = bv.x; a1 = bv.y; a2 = bv.z; a3 = bv.w;
    #pragma unroll 4
    for (int k0 = 0; k0 < 64; ++k0) {
        float g0 = __shfl(h0, k0), g1 = __shfl(h1, k0);
        float g2 = __shfl(h2, k0), g3 = __shfl(h3, k0);
        float4 w;
        w = W2T4[(4 * k0 + 0) * 64 + l]; a0 += w.x * g0; a1 += w.y * g0; a2 += w.z * g0; a3 += w.w * g0;
        w = W2T4[(4 * k0 + 1) * 64 + l]; a0 += w.x * g1; a1 += w.y * g1; a2 += w.z * g1; a3 += w.w * g1;
        w = W2T4[(4 * k0 + 2) * 64 + l]; a0 += w.x * g2; a1 += w.y * g2; a2 += w.z * g2; a3 += w.w * g2;
        w = W2T4[(4 * k0 + 3) * 64 + l]; a0 += w.x * g3; a1 += w.y * g3; a2 += w.z * g3; a3 += w.w * g3;
    }
    h0 = tanhf(a0); h1 = tanhf(a1); h2 = tanhf(a2); h3 = tanhf(a3);

    // ---- heads: 144 outputs, lanes 0..35 own 4 consecutive each ----
    float c0 = 0.f, c1 = 0.f, c2 = 0.f, c3 = 0.f;
    if (l < 36) {
        float4 bh = *(const float4*)&BH[4 * l];
        c0 = bh.x; c1 = bh.y; c2 = bh.z; c3 = bh.w;
    }
    #pragma unroll 4
    for (int k0 = 0; k0 < 64; ++k0) {
        float g0 = __shfl(h0, k0), g1 = __shfl(h1, k0);
        float g2 = __shfl(h2, k0), g3 = __shfl(h3, k0);
        if (l < 36) {
            float4 w;
            w = WHT4[(4 * k0 + 0) * 36 + l]; c0 += w.x * g0; c1 += w.y * g0; c2 += w.z * g0; c3 += w.w * g0;
            w = WHT4[(4 * k0 + 1) * 36 + l]; c0 += w.x * g1; c1 += w.y * g1; c2 += w.z * g1; c3 += w.w * g1;
            w = WHT4[(4 * k0 + 2) * 36 + l]; c0 += w.x * g2; c1 += w.y * g2; c2 += w.z * g2; c3 += w.w * g2;
            w = WHT4[(4 * k0 + 3) * 36 + l]; c0 += w.x * g3; c1 += w.y * g3; c2 += w.z * g3; c3 += w.w * g3;
        }
    }

    // ---- broadcast train times tt[0..15] (live in lanes 0..3) ----
    float ttv[16];
    #pragma unroll
    for (int i = 0; i < 16; ++i) {
        float src = ((i & 3) == 0) ? c0 : ((i & 3) == 1) ? c1 : ((i & 3) == 2) ? c2 : c3;
        ttv[i] = __shfl(src, i >> 2);
    }
    // alpha RHS: lane 48+a gathers y[a][0..15]
    float z2[16];
    #pragma unroll
    for (int i = 0; i < 16; ++i) {
        int src = (4 + 4 * (l - 48) + (i >> 2)) & 63;
        float v = ((i & 3) == 0) ? c0 : ((i & 3) == 1) ? c1 : ((i & 3) == 2) ? c2 : c3;
        z2[i] = __shfl(v, src);
    }

    // ---- K row for lane i (i<16) ----
    float tsel = ttv[0];
    #pragma unroll
    for (int i = 1; i < 16; ++i) tsel = (l == i) ? ttv[i] : tsel;
    float Krow[16];
    #pragma unroll
    for (int j = 0; j < 16; ++j) {
        float d = tsel - ttv[j];
        Krow[j] = SF2c * __expf(NEGHALF_INV_L2 * d * d) + ((l == j) ? SN2c : 0.f);
    }

    // ---- register Cholesky: lane i owns row i of L ----
    float Lrow[16];
    #pragma unroll
    for (int j = 0; j < 16; ++j) {
        float s = Krow[j];
        #pragma unroll
        for (int k = 0; k < j; ++k) {
            float Ljk = __shfl(Lrow[k], j);
            s -= Lrow[k] * Ljk;
        }
        float dj = __shfl(s, j);
        float dsq = sqrtf(dj);
        float rinv = 1.0f / dsq;
        Lrow[j] = (l == j) ? dsq : s * rinv;
    }

    // ---- Ks rows for this lane's two query points ----
    float Ksr0[16], Ksr1[16];
    #pragma unroll
    for (int i = 0; i < 16; ++i) {
        float d0 = tq2.x - ttv[i];
        float d1 = tq2.y - ttv[i];
        Ksr0[i] = SF2c * __expf(NEGHALF_INV_L2 * d0 * d0);
        Ksr1[i] = SF2c * __expf(NEGHALF_INV_L2 * d1 * d1);
    }
    float z0[16], z1[16];
    #pragma unroll
    for (int i = 0; i < 16; ++i) { z0[i] = Ksr0[i]; z1[i] = Ksr1[i]; }

    // ---- forward solve ----
    #pragma unroll
    for (int i = 0; i < 16; ++i) {
        #pragma unroll
        for (int k = 0; k < i; ++k) {
            float Lik = __shfl(Lrow[k], i);
            z0[i] -= Lik * z0[k];
            z1[i] -= Lik * z1[k];
            z2[i] -= Lik * z2[k];
        }
        float Lii = __shfl(Lrow[i], i);
        float r = 1.0f / Lii;
        z0[i] *= r; z1[i] *= r; z2[i] *= r;
    }
    // ---- backward solve ----
    #pragma unroll
    for (int i = 15; i >= 0; --i) {
        #pragma unroll
        for (int k = i + 1; k < 16; ++k) {
            float Lki = __shfl(Lrow[i], k);
            z0[i] -= Lki * z0[k];
            z1[i] -= Lki * z1[k];
            z2[i] -= Lki * z2[k];
        }
        float Lii = __shfl(Lrow[i], i);
        float r = 1.0f / Lii;
        z0[i] *= r; z1[i] *= r; z2[i] *= r;
    }

    // ---- store V and Ks for the cov kernel ----
    float* __restrict__ wsV = ws + OFF_V + (size_t)e * (Nn * Tt);
    #pragma unroll
    for (int i = 0; i < 16; ++i) {
        float2 p; p.x = z0[i]; p.y = z1[i];
        *(float2*)&wsV[i * Tt + 2 * l] = p;
    }
    float* __restrict__ wsK = ws + OFF_KS + (size_t)e * (Tt * Nn);
    #pragma unroll
    for (int m = 0; m < 4; ++m) {
        float4 p0; p0.x = Ksr0[4*m+0]; p0.y = Ksr0[4*m+1]; p0.z = Ksr0[4*m+2]; p0.w = Ksr0[4*m+3];
        *(float4*)&wsK[(2 * l) * Nn + 4 * m] = p0;
        float4 p1; p1.x = Ksr1[4*m+0]; p1.y = Ksr1[4*m+1]; p1.z = Ksr1[4*m+2]; p1.w = Ksr1[4*m+3];
        *(float4*)&wsK[(2 * l + 1) * Nn + 4 * m] = p1;
    }

    // ---- mu ----
    float* __restrict__ mub = out_mu + (size_t)e * (Aa * Tt);
    #pragma unroll
    for (int a = 0; a < Aa; ++a) {
        float m0 = 0.f, m1 = 0.f;
        #pragma unroll
        for (int i = 0; i < 16; ++i) {
            float al = __shfl(z2[i], 48 + a);
            m0 += Ksr0[i] * al;
            m1 += Ksr1[i] * al;
        }
        float2 p; p.x = m0; p.y = m1;
        *(float2*)&mub[a * Tt + 2 * l] = p;
    }
}

// ---- k2: cov for ONE (e,a) panel per block; contiguous 64 KB write, global
// write stream is linear in blockIdx (like fillBuffer). Math redundant 8x
// across anchors (compute is ~free); NO strided replicated stores. ----
__global__ __launch_bounds__(256, 4) void grp_cov_lin(
    const float* __restrict__ ws, const float* __restrict__ tarr,
    float* __restrict__ out_cov)
{
    const int b = blockIdx.x;          // b = e*8 + a  -> writes bytes [b*64KB, ...)
    const int e = b >> 3;
    const int tid = threadIdx.x;

    __shared__ __align__(16) float Vs[Nn][Tt];     // 8 KB
    __shared__ __align__(16) float Ksl[Tt][Nn];    // 8 KB
    __shared__ float tqs[Tt];

    {
        const float4* sV = (const float4*)(ws + OFF_V + (size_t)e * (Nn * Tt));
        float4* dV = (float4*)&Vs[0][0];
        dV[tid] = sV[tid];
        dV[tid + 256] = sV[tid + 256];
        const float4* sK = (const float4*)(ws + OFF_KS + (size_t)e * (Tt * Nn));
        float4* dK = (float4*)&Ksl[0][0];
        dK[tid] = sK[tid];
        dK[tid + 256] = sK[tid + 256];
        if (tid < Tt) tqs[tid] = tarr[tid];
    }
    __syncthreads();

    const int q4 = (tid & 31) * 4;     // 4 consecutive cols
    const int pg = tid >> 5;           // 8 row-groups of 16 rows
    float vq[Nn][4];
    #pragma unroll
    for (int i = 0; i < Nn; ++i) {
        float4 vv = *(const float4*)&Vs[i][q4];
        vq[i][0] = vv.x; vq[i][1] = vv.y; vq[i][2] = vv.z; vq[i][3] = vv.w;
    }
    const float tqq0 = tqs[q4 + 0], tqq1 = tqs[q4 + 1], tqq2 = tqs[q4 + 2], tqq3 = tqs[q4 + 3];
    float* __restrict__ panel = out_cov + (size_t)b * (Tt * Tt);

    #pragma unroll
    for (int pp = 0; pp < 16; ++pp) {
        const int p = pg * 16 + pp;
        const float tqp = tqs[p];
        float d0 = tqp - tqq0, d1 = tqp - tqq1, d2 = tqp - tqq2, d3 = tqp - tqq3;
        float a0 = SF2c * __expf(NEGHALF_INV_L2 * d0 * d0);
        float a1 = SF2c * __expf(NEGHALF_INV_L2 * d1 * d1);
        float a2 = SF2c * __expf(NEGHALF_INV_L2 * d2 * d2);
        float a3 = SF2c * __expf(NEGHALF_INV_L2 * d3 * d3);
        #pragma unroll
        for (int i = 0; i < Nn; ++i) {
            float ks = Ksl[p][i];
            a0 -= ks * vq[i][0];
            a1 -= ks * vq[i][1];
            a2 -= ks * vq[i][2];
            a3 -= ks * vq[i][3];
        }
        float4 pk; pk.x = a0; pk.y = a1; pk.z = a2; pk.w = a3;
        *(float4*)(panel + (size_t)p * Tt + q4) = pk;
    }
}

extern "C" void kernel_launch(void* const* d_in, const int* in_sizes, int n_in,
                              void* d_out, int out_size, void* d_ws, size_t ws_size,
                              hipStream_t stream) {
    (void)in_sizes; (void)n_in; (void)out_size; (void)ws_size;
    const float* x  = (const float*)d_in[0];
    // d_in[1] (a) and d_in[2] (da) unused by the reference
    const float* W1 = (const float*)d_in[3];
    const float* b1 = (const float*)d_in[4];
    const float* W2 = (const float*)d_in[5];
    const float* b2 = (const float*)d_in[6];
    const float* Wt = (const float*)d_in[7];
    const float* bt = (const float*)d_in[8];
    const float* Wa = (const float*)d_in[9];
    const float* ba = (const float*)d_in[10];
    const float* ta = (const float*)d_in[11];
    float* mu  = (float*)d_out;
    float* cov = mu + (size_t)Ecnt * Aa * Tt;
    float* wsf = (float*)d_ws;

    prep<<<(OFF_TT + 255) / 256, 256, 0, stream>>>(W1, W2, Wt, Wa, bt, ba, wsf);
    grp_solve_wave<<<Ecnt, 64, 0, stream>>>(x, b1, b2, ta, wsf, mu);
    grp_cov_lin<<<Ecnt * Aa, 256, 0, stream>>>(wsf, ta, cov);
}